// Round 11
// baseline (184.647 us; speedup 1.0000x reference)
//
#include <hip/hip_runtime.h>
#include <cstdint>
#include <cstddef>

#define THETA 1.2f
#define XI 0.3f
#define BDIM 8192
#define DDIM 512
#define NWORK 2112         // live blocks: sum_{p=0..127} (32 - (p>>2))
#define NPAIRS_UP (((double)BDIM * (double)(BDIM + 1)) * 0.5)

typedef float f32x4 __attribute__((ext_vector_type(4)));
typedef int i32x8 __attribute__((ext_vector_type(8)));

// Kernel 1: per-row L2 normalize fp32 -> fp8 e4m3, coalesced; sq[row]=||n||^2; zero counter.
__global__ __launch_bounds__(256) void normalize_rows(
    const float* __restrict__ x, unsigned char* __restrict__ nf8,
    float* __restrict__ sq, unsigned int* __restrict__ counter)
{
    if (blockIdx.x == 0 && threadIdx.x == 0) { *counter = 0u; }
    int row = blockIdx.x * 4 + (threadIdx.x >> 6);
    int l = threadIdx.x & 63;
    const float4* xr = (const float4*)(x + (size_t)row * DDIM);
    float4 f0 = xr[l];
    float4 f1 = xr[l + 64];
    float s = f0.x*f0.x + f0.y*f0.y + f0.z*f0.z + f0.w*f0.w
            + f1.x*f1.x + f1.y*f1.y + f1.z*f1.z + f1.w*f1.w;
    #pragma unroll
    for (int m = 1; m < 64; m <<= 1) s += __shfl_xor(s, m);
    float rn = rsqrtf(s);
    int pk0 = __builtin_amdgcn_cvt_pk_fp8_f32(f0.x * rn, f0.y * rn, 0, false);
    pk0     = __builtin_amdgcn_cvt_pk_fp8_f32(f0.z * rn, f0.w * rn, pk0, true);
    int pk1 = __builtin_amdgcn_cvt_pk_fp8_f32(f1.x * rn, f1.y * rn, 0, false);
    pk1     = __builtin_amdgcn_cvt_pk_fp8_f32(f1.z * rn, f1.w * rn, pk1, true);
    int* rowp = (int*)(nf8 + (size_t)row * DDIM);
    rowp[l] = pk0;
    rowp[l + 64] = pk1;
    if (l == 0) sq[row] = s * rn * rn;
}

// Kernel 2: grid (128,32): p = 64-row i-panel, g = 256-col j-group (y-slow -> co-launched
// blocks share g's 128-KB B-set in L2). A-panel 64x512 = 32 KB LDS staged once; each of
// 4 waves computes a 64x64 tile (jc = g*256 + w*64) with mfma_scale 16x16x128 fp8,
// B fragments direct from L2-hot global (single-buffered: TLP over ILP, VGPR <= 128
// so ~4 blocks/CU co-reside). Fused hinge, analytic XI, ticket finalize.
__global__ __launch_bounds__(256) void gram_hinge(
    const unsigned char* __restrict__ nf8, const float* __restrict__ sq,
    const int* __restrict__ y, double* __restrict__ part,
    unsigned int* __restrict__ counter, float* __restrict__ out)
{
    int p = blockIdx.x;
    int g = blockIdx.y;
    int a = p >> 2;
    if (g < a) return;               // block fully below diagonal

    __shared__ unsigned char As[64 * 512];   // 32 KB
    __shared__ float sqA[64];
    __shared__ int   yA[64];
    __shared__ float sqB[256];
    __shared__ int   yB[256];
    __shared__ float wpart[4];
    __shared__ double dpart[4];
    __shared__ int is_last;

    int tid = threadIdx.x;
    int w = tid >> 6, l = tid & 63;
    int lr = l & 15, q = l >> 4;

    // ---- stage A-panel (64 rows x 512 B), granule-swizzled, 8 DMA/wave ----
    const unsigned char* gA = nf8 + (size_t)p * 64 * DDIM;
    {
        int rl = l >> 5;             // row within segment pair
        int gl = l & 31;             // LDS granule within row
        #pragma unroll
        for (int i = 0; i < 8; ++i) {
            int s = i * 4 + w;       // segment 0..31 (2 rows each)
            int r = s * 2 + rl;
            int gg = gl ^ (r & 7);   // coalescing-safe in-row granule swizzle
            __builtin_amdgcn_global_load_lds(
                (const __attribute__((address_space(1))) void*)
                    (gA + (size_t)r * DDIM + gg * 16),
                (__attribute__((address_space(3))) void*)(As + s * 1024), 16, 0, 0);
        }
    }
    // ---- stage sq/y: A-rows (64) and this g's 256 cols ----
    {
        if (tid < 64) { sqA[tid] = sq[p * 64 + tid]; yA[tid] = y[p * 64 + tid]; }
        sqB[tid] = sq[g * 256 + tid];
        yB[tid]  = y[g * 256 + tid];
    }
    __syncthreads();   // single drain+barrier per block

    int pbase = p * 64;
    int jc = g * 256 + w * 64;       // this wave's j-origin
    float acc0 = 0.f, acc1 = 0.f, acc2 = 0.f, acc3 = 0.f;

    if (jc >= pbase) {               // wave-uniform: tile at/above diagonal
        f32x4 accv[4][4] = {};
        const unsigned char* rowB = nf8 + (size_t)(jc + lr) * DDIM + q * 32;

        #pragma unroll
        for (int it = 0; it < 4; ++it) {
            int k0 = it * 128;
            // B fragments (8 x b128 global, L2-hot)
            i32x8 bfr[4];
            #pragma unroll
            for (int ni = 0; ni < 4; ++ni) {
                const int4* bp = (const int4*)(rowB + (size_t)ni * 16 * DDIM + k0);
                int4 b0 = bp[0], b1 = bp[1];
                bfr[ni][0] = b0.x; bfr[ni][1] = b0.y; bfr[ni][2] = b0.z; bfr[ni][3] = b0.w;
                bfr[ni][4] = b1.x; bfr[ni][5] = b1.y; bfr[ni][6] = b1.z; bfr[ni][7] = b1.w;
            }
            // A per-mi from LDS (keeps live regs low)
            #pragma unroll
            for (int mi = 0; mi < 4; ++mi) {
                int r = mi * 16 + lr;
                int G0 = it * 8 + q * 2;
                int sw = r & 7;
                int4 a0 = *(const int4*)(As + r * 512 + ((G0 ^ sw) << 4));
                int4 a1 = *(const int4*)(As + r * 512 + (((G0 | 1) ^ sw) << 4));
                i32x8 af;
                af[0] = a0.x; af[1] = a0.y; af[2] = a0.z; af[3] = a0.w;
                af[4] = a1.x; af[5] = a1.y; af[6] = a1.z; af[7] = a1.w;
                #pragma unroll
                for (int ni = 0; ni < 4; ++ni)
                    accv[mi][ni] = __builtin_amdgcn_mfma_scale_f32_16x16x128_f8f6f4(
                        af, bfr[ni], accv[mi][ni],
                        0, 0, 0, 0x7F7F7F7F, 0, 0x7F7F7F7F);
            }
        }

        // ---- Epilogue (C/D: col=lane&15 (j), row=q*4+reg (i)) ----
        float sqj[4]; int yj[4];
        #pragma unroll
        for (int ni = 0; ni < 4; ++ni) {
            sqj[ni] = sqB[w * 64 + lr + ni * 16];
            yj[ni]  = yB[w * 64 + lr + ni * 16];
        }
        if (jc != pbase) {
            // strictly above diagonal: all 256 elements count
            #pragma unroll
            for (int mi = 0; mi < 4; ++mi) {
                #pragma unroll
                for (int r = 0; r < 4; ++r) {
                    int ia = mi * 16 + q * 4 + r;
                    float ci = THETA - sqA[ia];
                    int yi = yA[ia];
                    float h0 = fmaxf(fmaf(2.f, accv[mi][0][r], ci - sqj[0]), 0.f);
                    acc0 += (yi == yj[0]) ? h0 : -h0;
                    float h1 = fmaxf(fmaf(2.f, accv[mi][1][r], ci - sqj[1]), 0.f);
                    acc1 += (yi == yj[1]) ? h1 : -h1;
                    float h2 = fmaxf(fmaf(2.f, accv[mi][2][r], ci - sqj[2]), 0.f);
                    acc2 += (yi == yj[2]) ? h2 : -h2;
                    float h3 = fmaxf(fmaf(2.f, accv[mi][3][r], ci - sqj[3]), 0.f);
                    acc3 += (yi == yj[3]) ? h3 : -h3;
                }
            }
        } else {
            // diagonal tile: local col >= local row only
            #pragma unroll
            for (int mi = 0; mi < 4; ++mi) {
                #pragma unroll
                for (int r = 0; r < 4; ++r) {
                    int rl_ = mi * 16 + q * 4 + r;
                    float ci = THETA - sqA[rl_];
                    int yi = yA[rl_];
                    #pragma unroll
                    for (int ni = 0; ni < 4; ++ni) {
                        float h = fmaxf(fmaf(2.f, accv[mi][ni][r], ci - sqj[ni]), 0.f);
                        float sh = (yi == yj[ni]) ? h : -h;
                        if (lr + ni * 16 >= rl_) acc0 += sh;
                    }
                }
            }
        }
    }

    float local = (acc0 + acc1) + (acc2 + acc3);
    #pragma unroll
    for (int off = 32; off > 0; off >>= 1) local += __shfl_down(local, off);
    if (l == 0) wpart[w] = local;
    __syncthreads();
    if (tid == 0) {
        int b = p & 3;
        int idx = 32 * p - (2 * a * (a - 1) + a * b) + (g - a);   // compact live index
        double ssum = (double)wpart[0] + (double)wpart[1]
                    + (double)wpart[2] + (double)wpart[3];
        __hip_atomic_store(&part[idx], ssum, __ATOMIC_RELEASE, __HIP_MEMORY_SCOPE_AGENT);
        unsigned int ticket = __hip_atomic_fetch_add(
            counter, 1u, __ATOMIC_ACQ_REL, __HIP_MEMORY_SCOPE_AGENT);
        is_last = (ticket == NWORK - 1) ? 1 : 0;
    }
    __syncthreads();
    if (is_last) {
        double s = 0.0;
        for (int i = tid; i < NWORK; i += 256)
            s += __hip_atomic_load(&part[i], __ATOMIC_ACQUIRE, __HIP_MEMORY_SCOPE_AGENT);
        #pragma unroll
        for (int off = 32; off > 0; off >>= 1) s += __shfl_down(s, off);
        if (l == 0) dpart[w] = s;
        __syncthreads();
        if (tid == 0) {
            double total = (dpart[0] + dpart[1] + dpart[2] + dpart[3])
                         + (double)XI * NPAIRS_UP;
            const double m = 1.0 / ((double)BDIM * (double)BDIM - (double)BDIM);
            out[0] = (float)(total * m);
        }
    }
}

extern "C" void kernel_launch(void* const* d_in, const int* in_sizes, int n_in,
                              void* d_out, int out_size, void* d_ws, size_t ws_size,
                              hipStream_t stream) {
    const float* x = (const float*)d_in[0];
    const int* y = (const int*)d_in[1];
    float* out = (float*)d_out;

    unsigned char* nf8 = (unsigned char*)d_ws;                          // 4 MB fp8
    char* p = (char*)d_ws + (size_t)BDIM * DDIM;
    float* sq = (float*)p;                                              // 32 KB
    unsigned int* counter = (unsigned int*)(p + (size_t)BDIM * 4);
    double* part = (double*)(p + (size_t)BDIM * 4 + 64);                // NWORK doubles

    normalize_rows<<<BDIM / 4, 256, 0, stream>>>(x, nf8, sq, counter);
    gram_hinge<<<dim3(128, 32), 256, 0, stream>>>(nf8, sq, y, part, counter, out);
}

// Round 12
// 160.764 us; speedup vs baseline: 1.1486x; 1.1486x over previous
//
#include <hip/hip_runtime.h>
#include <cstdint>
#include <cstddef>

#define THETA 1.2f
#define XI 0.3f
#define BDIM 8192
#define DDIM 512
#define NWORK 1152         // live blocks: sum_{p=0..255} (8 - (p>>5))
#define NPAIRS_UP (((double)BDIM * (double)(BDIM + 1)) * 0.5)

typedef float f32x4 __attribute__((ext_vector_type(4)));
typedef int i32x8 __attribute__((ext_vector_type(8)));

// Kernel 1: per-row L2 normalize fp32 -> fp8 e4m3, coalesced; sq[row]=||n||^2; zero counter.
__global__ __launch_bounds__(256) void normalize_rows(
    const float* __restrict__ x, unsigned char* __restrict__ nf8,
    float* __restrict__ sq, unsigned int* __restrict__ counter)
{
    if (blockIdx.x == 0 && threadIdx.x == 0) { *counter = 0u; }
    int row = blockIdx.x * 4 + (threadIdx.x >> 6);
    int l = threadIdx.x & 63;
    const float4* xr = (const float4*)(x + (size_t)row * DDIM);
    float4 f0 = xr[l];
    float4 f1 = xr[l + 64];
    float s = f0.x*f0.x + f0.y*f0.y + f0.z*f0.z + f0.w*f0.w
            + f1.x*f1.x + f1.y*f1.y + f1.z*f1.z + f1.w*f1.w;
    #pragma unroll
    for (int m = 1; m < 64; m <<= 1) s += __shfl_xor(s, m);
    float rn = rsqrtf(s);
    int pk0 = __builtin_amdgcn_cvt_pk_fp8_f32(f0.x * rn, f0.y * rn, 0, false);
    pk0     = __builtin_amdgcn_cvt_pk_fp8_f32(f0.z * rn, f0.w * rn, pk0, true);
    int pk1 = __builtin_amdgcn_cvt_pk_fp8_f32(f1.x * rn, f1.y * rn, 0, false);
    pk1     = __builtin_amdgcn_cvt_pk_fp8_f32(f1.z * rn, f1.w * rn, pk1, true);
    int* rowp = (int*)(nf8 + (size_t)row * DDIM);
    rowp[l] = pk0;
    rowp[l + 64] = pk1;
    if (l == 0) sq[row] = s * rn * rn;
}

// Kernel 2: grid (256,8): p = 32-row i-panel (A = 16 KB LDS, staged once),
// g = 1024-col j-chunk (y-slow: co-launched blocks share g's B-set in L2).
// Each of 4 waves runs 4 sequential passes of a 32x64 tile (accv = 32 VGPRs)
// with mfma_scale 16x16x128 fp8; B direct from L2-hot global. Small register
// footprint (goal <= ~104 VGPR) -> ~5 waves/SIMD for latency hiding.
__global__ __launch_bounds__(256) void gram_hinge(
    const unsigned char* __restrict__ nf8, const float* __restrict__ sq,
    const int* __restrict__ y, double* __restrict__ part,
    unsigned int* __restrict__ counter, float* __restrict__ out)
{
    int p = blockIdx.x;              // 32-row panel
    int g = blockIdx.y;              // 1024-col chunk
    int c = p >> 5;
    if (g < c) return;               // block fully below diagonal

    __shared__ unsigned char As[32 * 512];   // 16 KB
    __shared__ float sqA[32];
    __shared__ int   yA[32];
    __shared__ float sqB[1024];
    __shared__ int   yB[1024];
    __shared__ float wpart[4];
    __shared__ double dpart[4];
    __shared__ int is_last;

    int tid = threadIdx.x;
    int w = tid >> 6, l = tid & 63;
    int lr = l & 15, q = l >> 4;
    int pbase = p * 32;

    // ---- stage A-panel (32 rows x 512 B): 4 DMA/wave, 1 KB contiguous each ----
    const unsigned char* gA = nf8 + (size_t)pbase * DDIM;
    {
        int rl = l >> 5;             // row within 2-row segment
        int gl = l & 31;             // granule within row
        #pragma unroll
        for (int i = 0; i < 4; ++i) {
            int s = i * 4 + w;       // segment 0..15
            int r = s * 2 + rl;
            int gg = gl ^ (r & 7);   // coalescing-safe in-row granule swizzle
            __builtin_amdgcn_global_load_lds(
                (const __attribute__((address_space(1))) void*)
                    (gA + (size_t)r * DDIM + gg * 16),
                (__attribute__((address_space(3))) void*)(As + s * 1024), 16, 0, 0);
        }
    }
    // ---- stage sq/y: 32 A-rows + 1024 B-cols ----
    {
        if (tid < 32) { sqA[tid] = sq[pbase + tid]; yA[tid] = y[pbase + tid]; }
        int cb = g * 1024;
        #pragma unroll
        for (int i = 0; i < 4; ++i) {
            sqB[tid + i * 256] = sq[cb + tid + i * 256];
            yB[tid + i * 256]  = y[cb + tid + i * 256];
        }
    }
    __syncthreads();   // single drain+barrier per block

    float acc0 = 0.f, acc1 = 0.f, acc2 = 0.f, acc3 = 0.f;

    #pragma unroll 1
    for (int pass = 0; pass < 4; ++pass) {
        int jc = g * 1024 + pass * 256 + w * 64;   // this wave's 64-col tile origin
        if (jc + 64 <= pbase) continue;            // fully below diagonal

        f32x4 accv[2][4] = {};
        const unsigned char* rowB = nf8 + (size_t)(jc + lr) * DDIM + q * 32;

        #pragma unroll
        for (int it = 0; it < 4; ++it) {
            int k0 = it * 128;
            i32x8 bfr[4];
            #pragma unroll
            for (int ni = 0; ni < 4; ++ni) {
                const int4* bp = (const int4*)(rowB + (size_t)ni * 16 * DDIM + k0);
                int4 b0 = bp[0], b1 = bp[1];
                bfr[ni][0] = b0.x; bfr[ni][1] = b0.y; bfr[ni][2] = b0.z; bfr[ni][3] = b0.w;
                bfr[ni][4] = b1.x; bfr[ni][5] = b1.y; bfr[ni][6] = b1.z; bfr[ni][7] = b1.w;
            }
            #pragma unroll
            for (int mi = 0; mi < 2; ++mi) {
                int r = mi * 16 + lr;
                int G0 = it * 8 + q * 2;
                int sw = r & 7;
                int4 a0 = *(const int4*)(As + r * 512 + ((G0 ^ sw) << 4));
                int4 a1 = *(const int4*)(As + r * 512 + (((G0 | 1) ^ sw) << 4));
                i32x8 af;
                af[0] = a0.x; af[1] = a0.y; af[2] = a0.z; af[3] = a0.w;
                af[4] = a1.x; af[5] = a1.y; af[6] = a1.z; af[7] = a1.w;
                #pragma unroll
                for (int ni = 0; ni < 4; ++ni)
                    accv[mi][ni] = __builtin_amdgcn_mfma_scale_f32_16x16x128_f8f6f4(
                        af, bfr[ni], accv[mi][ni],
                        0, 0, 0, 0x7F7F7F7F, 0, 0x7F7F7F7F);
            }
        }

        // ---- Epilogue (C/D: col=lane&15 (j), row=q*4+reg (i)) ----
        int job = pass * 256 + w * 64 + lr;        // index into sqB/yB
        float sqj[4]; int yj[4];
        #pragma unroll
        for (int ni = 0; ni < 4; ++ni) {
            sqj[ni] = sqB[job + ni * 16];
            yj[ni]  = yB[job + ni * 16];
        }
        if (jc >= pbase + 32) {
            // fully above diagonal
            #pragma unroll
            for (int mi = 0; mi < 2; ++mi) {
                #pragma unroll
                for (int r = 0; r < 4; ++r) {
                    int ia = mi * 16 + q * 4 + r;
                    float ci = THETA - sqA[ia];
                    int yi = yA[ia];
                    float h0 = fmaxf(fmaf(2.f, accv[mi][0][r], ci - sqj[0]), 0.f);
                    acc0 += (yi == yj[0]) ? h0 : -h0;
                    float h1 = fmaxf(fmaf(2.f, accv[mi][1][r], ci - sqj[1]), 0.f);
                    acc1 += (yi == yj[1]) ? h1 : -h1;
                    float h2 = fmaxf(fmaf(2.f, accv[mi][2][r], ci - sqj[2]), 0.f);
                    acc2 += (yi == yj[2]) ? h2 : -h2;
                    float h3 = fmaxf(fmaf(2.f, accv[mi][3][r], ci - sqj[3]), 0.f);
                    acc3 += (yi == yj[3]) ? h3 : -h3;
                }
            }
        } else {
            // straddles the diagonal: per-element gj >= gi test
            #pragma unroll
            for (int mi = 0; mi < 2; ++mi) {
                #pragma unroll
                for (int r = 0; r < 4; ++r) {
                    int gi = pbase + mi * 16 + q * 4 + r;
                    float ci = THETA - sqA[mi * 16 + q * 4 + r];
                    int yi = yA[mi * 16 + q * 4 + r];
                    #pragma unroll
                    for (int ni = 0; ni < 4; ++ni) {
                        int gj = jc + ni * 16 + lr;
                        float h = fmaxf(fmaf(2.f, accv[mi][ni][r], ci - sqj[ni]), 0.f);
                        float sh = (yi == yj[ni]) ? h : -h;
                        if (gj >= gi) acc0 += sh;
                    }
                }
            }
        }
    }

    float local = (acc0 + acc1) + (acc2 + acc3);
    #pragma unroll
    for (int off = 32; off > 0; off >>= 1) local += __shfl_down(local, off);
    if (l == 0) wpart[w] = local;
    __syncthreads();
    if (tid == 0) {
        // compact live index: sum_{p'<p}(8-(p'>>5)) + (g - c)
        int idx = 8 * p - (16 * c * (c - 1) + (p - 32 * c) * c) + (g - c);
        double ssum = (double)wpart[0] + (double)wpart[1]
                    + (double)wpart[2] + (double)wpart[3];
        __hip_atomic_store(&part[idx], ssum, __ATOMIC_RELEASE, __HIP_MEMORY_SCOPE_AGENT);
        unsigned int ticket = __hip_atomic_fetch_add(
            counter, 1u, __ATOMIC_ACQ_REL, __HIP_MEMORY_SCOPE_AGENT);
        is_last = (ticket == NWORK - 1) ? 1 : 0;
    }
    __syncthreads();
    if (is_last) {
        double s = 0.0;
        for (int i = tid; i < NWORK; i += 256)
            s += __hip_atomic_load(&part[i], __ATOMIC_ACQUIRE, __HIP_MEMORY_SCOPE_AGENT);
        #pragma unroll
        for (int off = 32; off > 0; off >>= 1) s += __shfl_down(s, off);
        if (l == 0) dpart[w] = s;
        __syncthreads();
        if (tid == 0) {
            double total = (dpart[0] + dpart[1] + dpart[2] + dpart[3])
                         + (double)XI * NPAIRS_UP;
            const double m = 1.0 / ((double)BDIM * (double)BDIM - (double)BDIM);
            out[0] = (float)(total * m);
        }
    }
}

extern "C" void kernel_launch(void* const* d_in, const int* in_sizes, int n_in,
                              void* d_out, int out_size, void* d_ws, size_t ws_size,
                              hipStream_t stream) {
    const float* x = (const float*)d_in[0];
    const int* y = (const int*)d_in[1];
    float* out = (float*)d_out;

    unsigned char* nf8 = (unsigned char*)d_ws;                          // 4 MB fp8
    char* p = (char*)d_ws + (size_t)BDIM * DDIM;
    float* sq = (float*)p;                                              // 32 KB
    unsigned int* counter = (unsigned int*)(p + (size_t)BDIM * 4);
    double* part = (double*)(p + (size_t)BDIM * 4 + 64);                // NWORK doubles

    normalize_rows<<<BDIM / 4, 256, 0, stream>>>(x, nf8, sq, counter);
    gram_hinge<<<dim3(256, 8), 256, 0, stream>>>(nf8, sq, y, part, counter, out);
}

// Round 13
// 132.756 us; speedup vs baseline: 1.3909x; 1.2110x over previous
//
#include <hip/hip_runtime.h>
#include <cstdint>
#include <cstddef>

#define THETA 1.2f
#define XI 0.3f
#define BDIM 8192
#define DDIM 512
#define NWORK 544          // jg-major triangular tiles: sum_{jg=0..15}(4*jg+4)
#define NPAIRS_UP (((double)BDIM * (double)(BDIM + 1)) * 0.5)

typedef float f32x4 __attribute__((ext_vector_type(4)));
typedef int i32x8 __attribute__((ext_vector_type(8)));

// Kernel 1: per-row L2 normalize fp32 -> fp8 e4m3, coalesced; sq[row]=||n||^2; zero counter.
__global__ __launch_bounds__(256) void normalize_rows(
    const float* __restrict__ x, unsigned char* __restrict__ nf8,
    float* __restrict__ sq, unsigned int* __restrict__ counter)
{
    if (blockIdx.x == 0 && threadIdx.x == 0) { *counter = 0u; }
    int row = blockIdx.x * 4 + (threadIdx.x >> 6);
    int l = threadIdx.x & 63;
    const float4* xr = (const float4*)(x + (size_t)row * DDIM);
    float4 f0 = xr[l];
    float4 f1 = xr[l + 64];
    float s = f0.x*f0.x + f0.y*f0.y + f0.z*f0.z + f0.w*f0.w
            + f1.x*f1.x + f1.y*f1.y + f1.z*f1.z + f1.w*f1.w;
    #pragma unroll
    for (int m = 1; m < 64; m <<= 1) s += __shfl_xor(s, m);
    float rn = rsqrtf(s);
    int pk0 = __builtin_amdgcn_cvt_pk_fp8_f32(f0.x * rn, f0.y * rn, 0, false);
    pk0     = __builtin_amdgcn_cvt_pk_fp8_f32(f0.z * rn, f0.w * rn, pk0, true);
    int pk1 = __builtin_amdgcn_cvt_pk_fp8_f32(f1.x * rn, f1.y * rn, 0, false);
    pk1     = __builtin_amdgcn_cvt_pk_fp8_f32(f1.z * rn, f1.w * rn, pk1, true);
    int* rowp = (int*)(nf8 + (size_t)row * DDIM);
    rowp[l] = pk0;
    rowp[l + 64] = pk1;
    if (l == 0) sq[row] = s * rn * rn;
}

// Kernel 2: R8 tiling (544 jg-major blocks, A-panel 128x512 = 64 KB LDS staged once,
// block covers 128 x 512 of C as 16 subtiles of 64x64) but with 512 threads = 8 waves:
// each wave computes 2 subtiles (s = w and w+8), doubling waves/CU at the same
// 2-blocks/CU LDS residency. Single-buffered B (8 b128 batch per K-iter), VGPR <= 128.
__global__ __launch_bounds__(512) void gram_hinge(
    const unsigned char* __restrict__ nf8, const float* __restrict__ sq,
    const int* __restrict__ y, double* __restrict__ part,
    unsigned int* __restrict__ counter, float* __restrict__ out)
{
    // jg-major decode, reversed: large jg (big B-sets) first
    int u = (NWORK - 1) - (int)blockIdx.x;
    int jg = (int)((sqrtf(1.0f + 2.0f * (float)u) - 1.0f) * 0.5f);
    while (2 * (jg + 1) * (jg + 2) <= u) ++jg;
    while (2 * jg * (jg + 1) > u) --jg;
    int bi = u - 2 * jg * (jg + 1);

    __shared__ unsigned char As[128 * 512];   // 64 KB A-panel, granule-swizzled rows
    __shared__ float sqA[128];
    __shared__ int   yA[128];
    __shared__ float sqB[512];
    __shared__ int   yB[512];
    __shared__ float wpart[8];
    __shared__ double dpart[8];
    __shared__ int is_last;

    int tid = threadIdx.x;
    int w = tid >> 6, l = tid & 63;     // 8 waves
    int lr = l & 15, q = l >> 4;

    // ---- stage A-panel once: 8 DMA instrs/wave (16 rows each wave), 1 KB contiguous ----
    const unsigned char* gA = nf8 + (size_t)bi * 128 * DDIM;
    {
        int rl = l >> 5;
        int gl = l & 31;
        #pragma unroll
        for (int i = 0; i < 8; ++i) {
            int rbase = w * 16 + i * 2;
            int r = rbase + rl;
            int gg = gl ^ (r & 7);   // in-row 16-B granule swizzle (coalescing-safe)
            __builtin_amdgcn_global_load_lds(
                (const __attribute__((address_space(1))) void*)(gA + (size_t)r * DDIM + gg * 16),
                (__attribute__((address_space(3))) void*)(As + rbase * 512), 16, 0, 0);
        }
    }
    // ---- stage sq/y: A-rows (128) + this jg's 512 cols ----
    {
        int arow = bi * 128;
        if (tid < 128) { sqA[tid] = sq[arow + tid]; yA[tid] = y[arow + tid]; }
        int cb = jg * 512;
        sqB[tid] = sq[cb + tid];
        yB[tid]  = y[cb + tid];
    }
    __syncthreads();   // single drain+barrier per block

    float acc0 = 0.f, acc1 = 0.f, acc2 = 0.f, acc3 = 0.f;

    #pragma unroll 1   // keep one pass's accv live at a time (register budget)
    for (int pass = 0; pass < 2; ++pass) {
        int s = w + pass * 8;            // subtile 0..15
        int jt = s >> 2;                 // j-tile 0..3
        int quad = s & 3;
        int wr = quad >> 1, wc = quad & 1;
        int bj = jg * 4 + jt;
        if (bj < bi) continue;           // subtile's j-tile below diagonal

        f32x4 accv[4][4] = {};
        const unsigned char* rowB =
            nf8 + ((size_t)(bj * 128 + wc * 64 + lr)) * DDIM + q * 32;

        #pragma unroll
        for (int it = 0; it < 4; ++it) {
            int k0 = it * 128;
            // B fragments: 8 b128 loads batch-issued, one waitcnt
            i32x8 bfr[4];
            #pragma unroll
            for (int ni = 0; ni < 4; ++ni) {
                const int4* bp = (const int4*)(rowB + (size_t)ni * 16 * DDIM + k0);
                int4 b0 = bp[0], b1 = bp[1];
                bfr[ni][0] = b0.x; bfr[ni][1] = b0.y; bfr[ni][2] = b0.z; bfr[ni][3] = b0.w;
                bfr[ni][4] = b1.x; bfr[ni][5] = b1.y; bfr[ni][6] = b1.z; bfr[ni][7] = b1.w;
            }
            // A fragments from LDS (granule-swizzled)
            #pragma unroll
            for (int mi = 0; mi < 4; ++mi) {
                int r = wr * 64 + mi * 16 + lr;
                int G0 = it * 8 + q * 2;
                int sw = r & 7;
                int4 a0 = *(const int4*)(As + r * 512 + ((G0 ^ sw) << 4));
                int4 a1 = *(const int4*)(As + r * 512 + (((G0 | 1) ^ sw) << 4));
                i32x8 af;
                af[0] = a0.x; af[1] = a0.y; af[2] = a0.z; af[3] = a0.w;
                af[4] = a1.x; af[5] = a1.y; af[6] = a1.z; af[7] = a1.w;
                #pragma unroll
                for (int ni = 0; ni < 4; ++ni)
                    accv[mi][ni] = __builtin_amdgcn_mfma_scale_f32_16x16x128_f8f6f4(
                        af, bfr[ni], accv[mi][ni],
                        0, 0, 0, 0x7F7F7F7F, 0, 0x7F7F7F7F);
            }
        }

        // ---- Epilogue (C/D: col=lane&15 (j), row=q*4+reg (i)) ----
        int jrow = jt * 128 + wc * 64 + lr;
        float sqj[4]; int yj[4];
        #pragma unroll
        for (int ni = 0; ni < 4; ++ni) {
            sqj[ni] = sqB[jrow + ni * 16];
            yj[ni]  = yB[jrow + ni * 16];
        }
        if (bj != bi) {
            #pragma unroll
            for (int mi = 0; mi < 4; ++mi) {
                #pragma unroll
                for (int r = 0; r < 4; ++r) {
                    int ia = wr * 64 + mi * 16 + q * 4 + r;
                    float ci = THETA - sqA[ia];
                    int yi = yA[ia];
                    float h0 = fmaxf(fmaf(2.f, accv[mi][0][r], ci - sqj[0]), 0.f);
                    acc0 += (yi == yj[0]) ? h0 : -h0;
                    float h1 = fmaxf(fmaf(2.f, accv[mi][1][r], ci - sqj[1]), 0.f);
                    acc1 += (yi == yj[1]) ? h1 : -h1;
                    float h2 = fmaxf(fmaf(2.f, accv[mi][2][r], ci - sqj[2]), 0.f);
                    acc2 += (yi == yj[2]) ? h2 : -h2;
                    float h3 = fmaxf(fmaf(2.f, accv[mi][3][r], ci - sqj[3]), 0.f);
                    acc3 += (yi == yj[3]) ? h3 : -h3;
                }
            }
        } else {
            // diagonal j-tile: local col (wc*64+lr+ni*16) >= local row (wr*64+mi*16+q*4+r)
            #pragma unroll
            for (int mi = 0; mi < 4; ++mi) {
                #pragma unroll
                for (int r = 0; r < 4; ++r) {
                    int rl_ = wr * 64 + mi * 16 + q * 4 + r;
                    float ci = THETA - sqA[rl_];
                    int yi = yA[rl_];
                    #pragma unroll
                    for (int ni = 0; ni < 4; ++ni) {
                        int cl = wc * 64 + lr + ni * 16;
                        float h = fmaxf(fmaf(2.f, accv[mi][ni][r], ci - sqj[ni]), 0.f);
                        float sh = (yi == yj[ni]) ? h : -h;
                        if (cl >= rl_) acc0 += sh;
                    }
                }
            }
        }
    }

    float local = (acc0 + acc1) + (acc2 + acc3);
    #pragma unroll
    for (int off = 32; off > 0; off >>= 1) local += __shfl_down(local, off);
    if (l == 0) wpart[w] = local;
    __syncthreads();
    if (tid == 0) {
        double ssum = 0.0;
        #pragma unroll
        for (int i = 0; i < 8; ++i) ssum += (double)wpart[i];
        __hip_atomic_store(&part[blockIdx.x], ssum, __ATOMIC_RELEASE, __HIP_MEMORY_SCOPE_AGENT);
        unsigned int ticket = __hip_atomic_fetch_add(
            counter, 1u, __ATOMIC_ACQ_REL, __HIP_MEMORY_SCOPE_AGENT);
        is_last = (ticket == NWORK - 1) ? 1 : 0;
    }
    __syncthreads();
    if (is_last) {
        double s = 0.0;
        for (int i = tid; i < NWORK; i += 512)
            s += __hip_atomic_load(&part[i], __ATOMIC_ACQUIRE, __HIP_MEMORY_SCOPE_AGENT);
        #pragma unroll
        for (int off = 32; off > 0; off >>= 1) s += __shfl_down(s, off);
        if (l == 0) dpart[w] = s;
        __syncthreads();
        if (tid == 0) {
            double total = 0.0;
            #pragma unroll
            for (int i = 0; i < 8; ++i) total += dpart[i];
            total += (double)XI * NPAIRS_UP;
            const double m = 1.0 / ((double)BDIM * (double)BDIM - (double)BDIM);
            out[0] = (float)(total * m);
        }
    }
}

extern "C" void kernel_launch(void* const* d_in, const int* in_sizes, int n_in,
                              void* d_out, int out_size, void* d_ws, size_t ws_size,
                              hipStream_t stream) {
    const float* x = (const float*)d_in[0];
    const int* y = (const int*)d_in[1];
    float* out = (float*)d_out;

    unsigned char* nf8 = (unsigned char*)d_ws;                          // 4 MB fp8
    char* p = (char*)d_ws + (size_t)BDIM * DDIM;
    float* sq = (float*)p;                                              // 32 KB
    unsigned int* counter = (unsigned int*)(p + (size_t)BDIM * 4);
    double* part = (double*)(p + (size_t)BDIM * 4 + 64);                // NWORK doubles

    normalize_rows<<<BDIM / 4, 256, 0, stream>>>(x, nf8, sq, counter);
    gram_hinge<<<NWORK, 512, 0, stream>>>(nf8, sq, y, part, counter, out);
}